// Round 1
// baseline (809.897 us; speedup 1.0000x reference)
//
#include <hip/hip_runtime.h>

// Problem geometry (fixed by reference setup_inputs)
static constexpr int Hh = 256, Ww = 256;
static constexpr int HW = Hh * Ww;
static constexpr int PLANES = 8 * 64;   // N * C

// slrelu(x) = 0.2*x + 0.8*softplus(10*x)/10, numerically stable softplus
__device__ __forceinline__ float slrelu_f(float x) {
    float z  = 10.0f * x;
    float az = fabsf(z);
    float e  = __expf(-az);          // exp(-|z|), never overflows
    float lp = __logf(1.0f + e);     // log1p(exp(-|z|))
    float sp = fmaxf(z, 0.0f) + lp;  // softplus(z)
    return fmaf(0.08f, sp, 0.2f * x);
}

// t0 = 1 - 2*slrelu(o), vectorized float4
__global__ __launch_bounds__(256) void k_init(const float* __restrict__ o,
                                              float* __restrict__ t0) {
    int i = blockIdx.x * blockDim.x + threadIdx.x;
    float4 o4 = reinterpret_cast<const float4*>(o)[i];
    float4 r;
    r.x = fmaf(-2.f, slrelu_f(o4.x), 1.f);
    r.y = fmaf(-2.f, slrelu_f(o4.y), 1.f);
    r.z = fmaf(-2.f, slrelu_f(o4.z), 1.f);
    r.w = fmaf(-2.f, slrelu_f(o4.w), 1.f);
    reinterpret_cast<float4*>(t0)[i] = r;
}

// One fixed-point iteration:
//   q = conv3x3_zero_pad(t_prev)  (separable Gaussian, per-channel sigma)
//   u = slrelu(o - lam*q)
//   out = FINAL ? u : 1 - 2*u
// Block = 256 threads = 4 waves; each wave owns one full image row
// (64 lanes x 4 px = 256 px). Horizontal neighbors via shuffles.
template<int FINAL>
__global__ __launch_bounds__(256) void k_iter(const float* __restrict__ tprev,
                                              const float* __restrict__ o,
                                              const float* __restrict__ sigma,
                                              const float* __restrict__ lam,
                                              float* __restrict__ out) {
    const int tid   = threadIdx.x;
    const int lane  = tid & 63;
    const int bid   = blockIdx.x;
    const int plane = bid >> 6;        // 512 (n,c) planes
    const int rg    = bid & 63;        // 64 groups of 4 rows
    const int y     = rg * 4 + (tid >> 6);
    const int x0    = lane * 4;
    const int ch    = plane & 63;

    // Per-channel separable weights: w1d = {e, 1, e} / (1 + 2e)
    float s   = fmaxf(sigma[ch], 1e-6f);
    float eg  = __expf(-1.0f / (2.0f * s * s));
    float inv = 1.0f / (1.0f + 2.0f * eg);
    const float w1 = inv;        // center tap
    const float w0 = eg * inv;   // edge tap
    const float l  = lam[0];

    const float* tp = tprev + plane * HW;

    // Horizontal 3-tap conv of one t-row (zero-padded in x and y)
    auto rowconv = [&](int yy, float* h) {
        float4 cv = make_float4(0.f, 0.f, 0.f, 0.f);
        if (yy >= 0 && yy < Hh)
            cv = *reinterpret_cast<const float4*>(tp + yy * Ww + x0);
        float lft = __shfl_up(cv.w, 1);
        if (lane == 0)  lft = 0.f;
        float rgt = __shfl_down(cv.x, 1);
        if (lane == 63) rgt = 0.f;
        h[0] = w0 * lft  + w1 * cv.x + w0 * cv.y;
        h[1] = w0 * cv.x + w1 * cv.y + w0 * cv.z;
        h[2] = w0 * cv.y + w1 * cv.z + w0 * cv.w;
        h[3] = w0 * cv.z + w1 * cv.w + w0 * rgt;
    };

    float h0[4], h1[4], h2[4];
    rowconv(y - 1, h0);
    rowconv(y,     h1);
    rowconv(y + 1, h2);

    const float4 o4 = *reinterpret_cast<const float4*>(o + plane * HW + y * Ww + x0);
    float ov[4] = {o4.x, o4.y, o4.z, o4.w};

    float r[4];
#pragma unroll
    for (int i = 0; i < 4; ++i) {
        float q = w0 * h0[i] + w1 * h1[i] + w0 * h2[i];   // vertical 3-tap
        float u = slrelu_f(fmaf(-l, q, ov[i]));
        r[i] = FINAL ? u : fmaf(-2.f, u, 1.f);
    }

    *reinterpret_cast<float4*>(out + plane * HW + y * Ww + x0) =
        make_float4(r[0], r[1], r[2], r[3]);
}

extern "C" void kernel_launch(void* const* d_in, const int* in_sizes, int n_in,
                              void* d_out, int out_size, void* d_ws, size_t ws_size,
                              hipStream_t stream) {
    (void)in_sizes; (void)n_in; (void)out_size; (void)ws_size;
    const float* o     = (const float*)d_in[0];
    const float* sigma = (const float*)d_in[1];
    const float* lam   = (const float*)d_in[2];
    float* out = (float*)d_out;
    float* ws  = (float*)d_ws;   // needs PLANES*HW*4 = 134 MB (one t buffer)

    // t0 -> d_out
    const int total4 = PLANES * HW / 4;          // 8388608
    k_init<<<total4 / 256, 256, 0, stream>>>(o, out);

    // Iterations 1..9 produce t_k, ping-pong: odd k -> ws, even k -> d_out.
    // t9 lands in ws, so the final pass reads ws and writes u into d_out
    // (no same-buffer read/write race).
    dim3 grid(PLANES * 64);
    const float* src = out;
    for (int k = 1; k <= 9; ++k) {
        float* dst = (k & 1) ? ws : out;
        k_iter<0><<<grid, 256, 0, stream>>>(src, o, sigma, lam, dst);
        src = dst;
    }
    k_iter<1><<<grid, 256, 0, stream>>>(src, o, sigma, lam, out);
}

// Round 2
// 381.051 us; speedup vs baseline: 2.1254x; 2.1254x over previous
//
#include <hip/hip_runtime.h>

// Problem geometry (fixed by reference setup_inputs)
static constexpr int Hh = 256, Ww = 256;
static constexpr int HW = Hh * Ww;
static constexpr int PLANES = 8 * 64;     // N * C = 512
static constexpr int STRIPS = 4;          // y-strips per plane
static constexpr int ROWS   = Hh / STRIPS;  // 64 output rows per strip
static constexpr int DEPTH  = 10;         // fixed-point iterations

// softplus(z) = max(z,0) + log1p(exp(-|z|)), stable for |z| up to ~60
__device__ __forceinline__ float sp_from_z(float z) {
    float e  = __expf(-fabsf(z));
    float lp = __logf(1.0f + e);
    return fmaxf(z, 0.0f) + lp;
}

// Fused 10-iteration line-sweep pipeline.
// grid = PLANES*STRIPS blocks x 64 threads (1 wave). Each wave sweeps a
// 64-row strip with an 11-stage register pipeline:
//   stage 0:  t0[y]   = 1 - 2*slrelu(o[y])            (z = 10*o)
//   stage k:  z = 10*(o[r] - l*q), q = sep-conv3x3(t_{k-1}) at row r=y-k
//             t_k = 1 - 0.04 z - 0.16 softplus(z)     (== 1-2*slrelu(z/10))
//   stage 10: u = 0.02 z + 0.08 softplus(z)  -> store
// Horizontal conv: 4 px/thread float4 + 2 shuffles (zero-pad at x edges).
// Vertical conv folded with the -10*l scale: z = W0*(hA+hn) + W1*hB + o10.
// Rows outside [0,255] contribute exactly 0 (the conv's zero padding).
__global__ __launch_bounds__(64, 2)
void k_fused(const float* __restrict__ o, const float* __restrict__ sigma,
             const float* __restrict__ lam, float* __restrict__ out) {
    const int lane  = threadIdx.x;         // 0..63
    const int bid   = blockIdx.x;
    const int plane = bid >> 2;            // 512 planes
    const int strip = bid & 3;
    const int y0    = strip * ROWS;
    const int x0    = lane * 4;
    const int ch    = plane & 63;

    // Per-channel separable weights: w1d = {e, 1, e} / (1 + 2e)
    float s   = fmaxf(sigma[ch], 1e-6f);
    float eg  = __expf(-1.0f / (2.0f * s * s));
    float inv = 1.0f / (1.0f + 2.0f * eg);
    const float w0 = eg * inv;             // edge tap
    const float w1 = inv;                  // center tap
    const float l  = lam[0];
    const float W0 = -10.0f * l * w0;      // fold -10*l into vertical taps
    const float W1 = -10.0f * l * w1;

    const float* op = o + plane * HW;
    float*       up = out + plane * HW;

    // Register state
    float oR[11][4];               // oR[j] = 10*o row (y-(10-j)); oR[10]=row y
    float hA[11][4], hB[11][4];    // stage k: h(r-1), h(r) of t_{k-1}
#pragma unroll
    for (int j = 0; j < 11; ++j)
#pragma unroll
        for (int i = 0; i < 4; ++i) { oR[j][i] = 0.f; hA[j][i] = 0.f; hB[j][i] = 0.f; }

    float ufin[4];

#pragma unroll 2
    for (int sstep = 0; sstep < ROWS + 2 * DEPTH; ++sstep) {   // 84 steps
        const int y = y0 - DEPTH + sstep;

        // shift o-ring, load new row y (zeros outside the image)
#pragma unroll
        for (int j = 0; j < 10; ++j)
#pragma unroll
            for (int i = 0; i < 4; ++i) oR[j][i] = oR[j + 1][i];
        if ((unsigned)y < 256u) {
            float4 v = *reinterpret_cast<const float4*>(op + y * Ww + x0);
            oR[10][0] = 10.f * v.x; oR[10][1] = 10.f * v.y;
            oR[10][2] = 10.f * v.z; oR[10][3] = 10.f * v.w;
        } else {
#pragma unroll
            for (int i = 0; i < 4; ++i) oR[10][i] = 0.f;
        }

        // stage 0: t0 row y (z = 10*o directly)
        float tin[4];
        {
            const bool valid = (unsigned)y < 256u;
#pragma unroll
            for (int i = 0; i < 4; ++i) {
                float z  = oR[10][i];
                float sp = sp_from_z(z);
                float t  = fmaf(-0.16f, sp, fmaf(-0.04f, z, 1.0f));
                tin[i] = valid ? t : 0.f;
            }
        }

        // stages 1..10
#pragma unroll
        for (int k = 1; k <= 10; ++k) {
            const int r = y - k;
            // horizontal 3-tap conv of tin (stage k-1's row r+1)
            float lft = __shfl_up(tin[3], 1);
            if (lane == 0)  lft = 0.f;
            float rgt = __shfl_down(tin[0], 1);
            if (lane == 63) rgt = 0.f;
            float hn[4];
            hn[0] = fmaf(w0, lft,    fmaf(w1, tin[0], w0 * tin[1]));
            hn[1] = fmaf(w0, tin[0], fmaf(w1, tin[1], w0 * tin[2]));
            hn[2] = fmaf(w0, tin[1], fmaf(w1, tin[2], w0 * tin[3]));
            hn[3] = fmaf(w0, tin[2], fmaf(w1, tin[3], w0 * rgt));

            const bool valid = (unsigned)r < 256u;
#pragma unroll
            for (int i = 0; i < 4; ++i) {
                // z = 10*(o[r] - l*q) = W0*(h(r-1)+h(r+1)) + W1*h(r) + 10*o[r]
                float z = fmaf(W0, hA[k][i] + hn[i],
                           fmaf(W1, hB[k][i], oR[10 - k][i]));
                float sp = sp_from_z(z);
                if (k < 10) {
                    float t = fmaf(-0.16f, sp, fmaf(-0.04f, z, 1.0f));
                    tin[i] = valid ? t : 0.f;
                } else {
                    ufin[i] = fmaf(0.08f, sp, 0.02f * z);
                }
                hA[k][i] = hB[k][i];
                hB[k][i] = hn[i];
            }
        }

        // store stage-10 output row r = y-10 when inside this strip
        const int r = y - DEPTH;
        if (r >= y0 && r < y0 + ROWS) {
            *reinterpret_cast<float4*>(up + r * Ww + x0) =
                make_float4(ufin[0], ufin[1], ufin[2], ufin[3]);
        }
    }
}

extern "C" void kernel_launch(void* const* d_in, const int* in_sizes, int n_in,
                              void* d_out, int out_size, void* d_ws, size_t ws_size,
                              hipStream_t stream) {
    (void)in_sizes; (void)n_in; (void)out_size; (void)d_ws; (void)ws_size;
    const float* o     = (const float*)d_in[0];
    const float* sigma = (const float*)d_in[1];
    const float* lam   = (const float*)d_in[2];
    float* out = (float*)d_out;

    k_fused<<<PLANES * STRIPS, 64, 0, stream>>>(o, sigma, lam, out);
}

// Round 3
// 295.344 us; speedup vs baseline: 2.7422x; 1.2902x over previous
//
#include <hip/hip_runtime.h>

typedef float f2 __attribute__((ext_vector_type(2)));
typedef float f4 __attribute__((ext_vector_type(4)));

static constexpr int Hh = 256, Ww = 256, HW = Hh * Ww;
static constexpr int PLANES = 512;          // N*C
static constexpr int STRIPS = 4;
static constexpr int ROWS   = Hh / STRIPS;  // 64
static constexpr int DEPTH  = 10;

#if __has_builtin(__builtin_amdgcn_exp2f)
#define EXP2F(x) __builtin_amdgcn_exp2f(x)
#else
#define EXP2F(x) __expf((x) * 0.6931471805599453f)
#endif
#if __has_builtin(__builtin_amdgcn_logf)
#define LOG2F(x) __builtin_amdgcn_logf(x)
#else
#define LOG2F(x) (__logf(x) * 1.4426950408889634f)
#endif

struct Consts {
    f2 w0, w1;        // horizontal taps
    f2 W0, W1;        // vertical taps with -10*lam folded
    f2 ten;           // {10,10}
    f2 c1, c2, c3;    // t = c1*lg + c2*max(z,0) + c3*z + 1
    f2 d1, d2, d3;    // u = d1*lg + d2*max(z,0) + d3*z
    f2 l2e, one;
};

__device__ __forceinline__ f2 pkfma(f2 a, f2 b, f2 c) {
#if __has_builtin(__builtin_elementwise_fma)
    return __builtin_elementwise_fma(a, b, c);
#else
    return f2{fmaf(a.x, b.x, c.x), fmaf(a.y, b.y, c.y)};
#endif
}
__device__ __forceinline__ f2 pkmax(f2 a, f2 b) {
#if __has_builtin(__builtin_elementwise_max)
    return __builtin_elementwise_max(a, b);
#else
    return f2{fmaxf(a.x, b.x), fmaxf(a.y, b.y)};
#endif
}

// shared softplus front-end: az=|z|, p=2^(-az*log2e), lg=log2(1+p), mz=max(z,0)
__device__ __forceinline__ void sp_parts(f2 z, const Consts& C, f2& lg, f2& mz) {
    f2 az = pkmax(z, -z);
    f2 a  = az * C.l2e;
    f2 p;
    p.x = EXP2F(-a.x);
    p.y = EXP2F(-a.y);
    f2 op = p + 1.0f;
    lg.x = LOG2F(op.x);
    lg.y = LOG2F(op.y);
    mz = pkmax(z, f2{0.f, 0.f});
}
// t = 1 - 2*slrelu(z/10) with z = 10*(o - lam*q)
__device__ __forceinline__ f2 tval(f2 z, const Consts& C) {
    f2 lg, mz;
    sp_parts(z, C, lg, mz);
    return pkfma(C.c1, lg, pkfma(C.c2, mz, pkfma(C.c3, z, C.one)));
}
// u = slrelu(z/10)
__device__ __forceinline__ f2 uval(f2 z, const Consts& C) {
    f2 lg, mz;
    sp_parts(z, C, lg, mz);
    return pkfma(C.d1, lg, pkfma(C.d2, mz, C.d3 * z));
}

// horizontal 3-tap conv of tin (4 px/lane as 2 f2), zero-padded at x edges
__device__ __forceinline__ void hconv(const f2 (&t)[2], f2 (&h)[2],
                                      int a_up, int a_dn, int lane, const Consts& C) {
    float lft = __int_as_float(__builtin_amdgcn_ds_bpermute(a_up, __float_as_int(t[1].y)));
    float rgt = __int_as_float(__builtin_amdgcn_ds_bpermute(a_dn, __float_as_int(t[0].x)));
    lft = (lane == 0)  ? 0.f : lft;
    rgt = (lane == 63) ? 0.f : rgt;
    f2 tl0 = {lft,    t[0].x};
    f2 mid = {t[0].y, t[1].x};   // right-nbrs of f2#0 == left-nbrs of f2#1
    f2 tr1 = {t[1].y, rgt};
    h[0] = pkfma(C.w1, t[0], C.w0 * (tl0 + mid));
    h[1] = pkfma(C.w1, t[1], C.w0 * (mid + tr1));
}

// one sweep step at image row yy; h-role rotation: (hA,hB) = rows (r-1, r)
// of each stage's h; hN receives row r+1. Roles rotate at the call site.
__device__ __forceinline__ void stepf(f2 (&hA)[10][2], f2 (&hB)[10][2], f2 (&hN)[10][2],
                                      int yy, int y0, const float* __restrict__ op_lane,
                                      float* __restrict__ up_lane, int lane,
                                      int a_up, int a_dn, const Consts& C) {
    // issue all o-row loads up front (L1/L2-hot; zeros outside the image)
    f2 orow[11][2];
#pragma unroll
    for (int k = 0; k <= 10; ++k) {
        const int r = yy - k;
        orow[k][0] = f2{0.f, 0.f};
        orow[k][1] = f2{0.f, 0.f};
        if ((unsigned)r < 256u) {
            f4 v = *reinterpret_cast<const f4*>(op_lane + r * Ww);
            orow[k][0] = f2{v.x, v.y};
            orow[k][1] = f2{v.z, v.w};
        }
    }

    // stage 0: t0[yy], z = 10*o
    f2 tin[2];
    tin[0] = tval(C.ten * orow[0][0], C);
    tin[1] = tval(C.ten * orow[0][1], C);
    if ((unsigned)yy >= 256u) { tin[0] = f2{0.f, 0.f}; tin[1] = f2{0.f, 0.f}; }

    f2 ufin[2];
#pragma unroll
    for (int k = 1; k <= 10; ++k) {
        f2 hn[2];
        hconv(tin, hn, a_up, a_dn, lane, C);
        const int r = yy - k;
#pragma unroll
        for (int i = 0; i < 2; ++i) {
            // z = 10*(o[r] - lam*q) = W0*(h(r-1)+h(r+1)) + W1*h(r) + 10*o[r]
            f2 z = pkfma(C.W0, hA[k - 1][i] + hn[i],
                   pkfma(C.W1, hB[k - 1][i], C.ten * orow[k][i]));
            if (k < 10) tin[i]  = tval(z, C);
            else        ufin[i] = uval(z, C);
            hN[k - 1][i] = hn[i];
        }
        if (k < 10 && (unsigned)r >= 256u) { tin[0] = f2{0.f, 0.f}; tin[1] = f2{0.f, 0.f}; }
    }

    // store u row r = yy-10 when inside this strip
    const int r = yy - DEPTH;
    if (r >= y0 && r < y0 + ROWS) {
        f4 v;
        v.x = ufin[0].x; v.y = ufin[0].y; v.z = ufin[1].x; v.w = ufin[1].y;
        *reinterpret_cast<f4*>(up_lane + r * Ww) = v;
    }
}

__global__ __launch_bounds__(64, 2)
void k_fused(const float* __restrict__ o, const float* __restrict__ sigma,
             const float* __restrict__ lam, float* __restrict__ out) {
    const int lane  = threadIdx.x;
    const int bid   = blockIdx.x;
    const int plane = bid >> 2;
    const int strip = bid & 3;
    const int y0    = strip * ROWS;
    const int x0    = lane * 4;
    const int ch    = plane & 63;

    float s   = fmaxf(sigma[ch], 1e-6f);
    float eg  = __expf(-1.0f / (2.0f * s * s));
    float inv = 1.0f / (1.0f + 2.0f * eg);
    float w0  = eg * inv, w1 = inv, l = lam[0];
    const float ln2 = 0.6931471805599453f;

    Consts C;
    C.w0  = f2{w0, w0};  C.w1 = f2{w1, w1};
    float Wa = -10.f * l * w0, Wb = -10.f * l * w1;
    C.W0  = f2{Wa, Wa};  C.W1 = f2{Wb, Wb};
    C.ten = f2{10.f, 10.f};
    C.c1  = f2{-0.16f * ln2, -0.16f * ln2};
    C.c2  = f2{-0.16f, -0.16f};
    C.c3  = f2{-0.04f, -0.04f};
    C.d1  = f2{0.08f * ln2, 0.08f * ln2};
    C.d2  = f2{0.08f, 0.08f};
    C.d3  = f2{0.02f, 0.02f};
    C.l2e = f2{1.4426950408889634f, 1.4426950408889634f};
    C.one = f2{1.f, 1.f};

    const float* op_lane = o   + plane * HW + x0;
    float*       up_lane = out + plane * HW + x0;
    const int a_up = ((lane + 63) & 63) << 2;
    const int a_dn = ((lane + 1)  & 63) << 2;

    f2 h0[10][2], h1[10][2], h2[10][2];
#pragma unroll
    for (int k = 0; k < 10; ++k)
#pragma unroll
        for (int i = 0; i < 2; ++i) {
            h0[k][i] = f2{0.f, 0.f};
            h1[k][i] = f2{0.f, 0.f};
            h2[k][i] = f2{0.f, 0.f};
        }

    int yy = y0 - DEPTH;
#pragma unroll 1
    for (int j = 0; j < 28; ++j) {   // 84 steps = 28 x 3-role rotation
        stepf(h0, h1, h2, yy + 0, y0, op_lane, up_lane, lane, a_up, a_dn, C);
        stepf(h1, h2, h0, yy + 1, y0, op_lane, up_lane, lane, a_up, a_dn, C);
        stepf(h2, h0, h1, yy + 2, y0, op_lane, up_lane, lane, a_up, a_dn, C);
        yy += 3;
    }
}

extern "C" void kernel_launch(void* const* d_in, const int* in_sizes, int n_in,
                              void* d_out, int out_size, void* d_ws, size_t ws_size,
                              hipStream_t stream) {
    (void)in_sizes; (void)n_in; (void)out_size; (void)d_ws; (void)ws_size;
    const float* o     = (const float*)d_in[0];
    const float* sigma = (const float*)d_in[1];
    const float* lam   = (const float*)d_in[2];
    float* out = (float*)d_out;

    k_fused<<<PLANES * STRIPS, 64, 0, stream>>>(o, sigma, lam, out);
}

// Round 4
// 255.242 us; speedup vs baseline: 3.1731x; 1.1571x over previous
//
#include <hip/hip_runtime.h>

typedef float f2 __attribute__((ext_vector_type(2)));
typedef float f4 __attribute__((ext_vector_type(4)));

static constexpr int Hh = 256, Ww = 256, HW = Hh * Ww;
static constexpr int PLANES = 512;            // N*C
static constexpr int STRIPS = 4;
static constexpr int ROWS   = Hh / STRIPS;    // 64
static constexpr int DEPTH  = 10;
static constexpr int RB     = 4;              // rows advanced per sweep step
static constexpr int NSTEP  = (ROWS + 2 * DEPTH) / RB;   // 21

#if __has_builtin(__builtin_amdgcn_exp2f)
#define EXP2F(x) __builtin_amdgcn_exp2f(x)
#else
#define EXP2F(x) __expf((x) * 0.6931471805599453f)
#endif
#if __has_builtin(__builtin_amdgcn_logf)
#define LOG2F(x) __builtin_amdgcn_logf(x)
#else
#define LOG2F(x) (__logf(x) * 1.4426950408889634f)
#endif

__device__ __forceinline__ f2 pkfma(f2 a, f2 b, f2 c) {
#if __has_builtin(__builtin_elementwise_fma)
    return __builtin_elementwise_fma(a, b, c);
#else
    return f2{fmaf(a.x, b.x, c.x), fmaf(a.y, b.y, c.y)};
#endif
}
__device__ __forceinline__ f2 pkmax(f2 a, f2 b) {
#if __has_builtin(__builtin_elementwise_max)
    return __builtin_elementwise_max(a, b);
#else
    return f2{fmaxf(a.x, b.x), fmaxf(a.y, b.y)};
#endif
}

static constexpr float LN2 = 0.6931471805599453f;
static constexpr float L2E = 1.4426950408889634f;

// softplus front-end in base 2: lg = log2(1 + 2^(-|z|*log2e)), mz = max(z,0)
__device__ __forceinline__ void sp_parts(f2 z, f2& lg, f2& mz) {
    f2 az = pkmax(z, -z);
    f2 a  = az * L2E;
    f2 p;
    p.x = EXP2F(-a.x);
    p.y = EXP2F(-a.y);
    f2 op = p + 1.0f;
    lg.x = LOG2F(op.x);
    lg.y = LOG2F(op.y);
    mz = pkmax(z, f2{0.f, 0.f});
}
// t = 1 - 2*slrelu(z/10) = 1 - 0.04 z - 0.16 (mz + ln2*lg)
__device__ __forceinline__ f2 tval(f2 z) {
    f2 lg, mz;
    sp_parts(z, lg, mz);
    return pkfma(f2{-0.16f * LN2, -0.16f * LN2}, lg,
           pkfma(f2{-0.16f, -0.16f}, mz,
           pkfma(f2{-0.04f, -0.04f}, z, f2{1.f, 1.f})));
}
// u = slrelu(z/10) = 0.02 z + 0.08 (mz + ln2*lg)
__device__ __forceinline__ f2 uval(f2 z) {
    f2 lg, mz;
    sp_parts(z, lg, mz);
    return pkfma(f2{0.08f * LN2, 0.08f * LN2}, lg,
           pkfma(f2{0.08f, 0.08f}, mz, f2{0.02f, 0.02f} * z));
}

__global__ __launch_bounds__(64, 2)
void k_fused(const float* __restrict__ o, const float* __restrict__ sigma,
             const float* __restrict__ lam, float* __restrict__ out) {
    const int lane  = threadIdx.x;
    const int bid   = blockIdx.x;
    const int plane = bid >> 2;
    const int strip = bid & 3;
    const int y0    = strip * ROWS;
    const int x0    = lane * 4;
    const int ch    = plane & 63;

    float s   = fmaxf(sigma[ch], 1e-6f);
    float eg  = __expf(-1.0f / (2.0f * s * s));
    float inv = 1.0f / (1.0f + 2.0f * eg);
    const float w0s = eg * inv, w1s = inv, l = lam[0];
    const f2 w0 = f2{w0s, w0s}, w1 = f2{w1s, w1s};
    const f2 W0 = f2{-10.f * l * w0s, -10.f * l * w0s};
    const f2 W1 = f2{-10.f * l * w1s, -10.f * l * w1s};

    const float* op_lane = o   + plane * HW + x0;
    float*       up_lane = out + plane * HW + x0;
    const int a_up = ((lane + 63) & 63) << 2;
    const int a_dn = ((lane + 1)  & 63) << 2;

    // per-stage h carries: rows (r-1, r) of conv'd t_{k-1}
    f2 hA[DEPTH][2], hB[DEPTH][2];
#pragma unroll
    for (int k = 0; k < DEPTH; ++k)
#pragma unroll
        for (int i = 0; i < 2; ++i) { hA[k][i] = f2{0.f, 0.f}; hB[k][i] = f2{0.f, 0.f}; }

#pragma unroll 1
    for (int j = 0; j < NSTEP; ++j) {
        const int yS = y0 - DEPTH + RB * j;   // fresh stage-0 rows yS..yS+3

        // ---- load o rows yS-10 .. yS+3 (14 rows), zero outside the image ----
        f2 orow[DEPTH + RB][2];
#pragma unroll
        for (int t = 0; t < DEPTH + RB; ++t) {
            const int r = yS - DEPTH + t;
            orow[t][0] = f2{0.f, 0.f};
            orow[t][1] = f2{0.f, 0.f};
            if ((unsigned)r < 256u) {
                f4 v = *reinterpret_cast<const f4*>(op_lane + r * Ww);
                orow[t][0] = f2{v.x, v.y};
                orow[t][1] = f2{v.z, v.w};
            }
        }
        asm volatile("" ::: "memory");   // pin the load batch above the compute

        // ---- stage 0: t0 rows yS..yS+3 (orow slots 10..13) ----
        f2 tin[RB][2];
#pragma unroll
        for (int m = 0; m < RB; ++m) {
            const int r = yS + m;
            const bool rv = (unsigned)r < 256u;
#pragma unroll
            for (int i = 0; i < 2; ++i) {
                f2 t = tval(10.f * orow[DEPTH + m][i]);
                tin[m][i] = rv ? t : f2{0.f, 0.f};
            }
        }

        f2 ufin[RB][2];
        // ---- stages 1..10 ----
#pragma unroll
        for (int k = 1; k <= DEPTH; ++k) {
            // horizontal conv of the 4 incoming t rows -> hn[m] = h(yS-k+1+m)
            f2 hn[RB][2];
#pragma unroll
            for (int m = 0; m < RB; ++m) {
                const f2 t0 = tin[m][0], t1 = tin[m][1];
                float lft = __int_as_float(__builtin_amdgcn_ds_bpermute(a_up, __float_as_int(t1.y)));
                float rgt = __int_as_float(__builtin_amdgcn_ds_bpermute(a_dn, __float_as_int(t0.x)));
                lft = (lane == 0)  ? 0.f : lft;
                rgt = (lane == 63) ? 0.f : rgt;
                f2 tl0 = {lft,  t0.x};
                f2 mid = {t0.y, t1.x};
                f2 tr1 = {t1.y, rgt};
                hn[m][0] = pkfma(w1, t0, w0 * (tl0 + mid));
                hn[m][1] = pkfma(w1, t1, w0 * (mid + tr1));
            }
            // z rows r = yS-k+m ; o slot = 10-k+m
#pragma unroll
            for (int m = 0; m < RB; ++m) {
                const int r = yS - k + m;
                const bool rv = (unsigned)r < 256u;
#pragma unroll
                for (int i = 0; i < 2; ++i) {
                    // value-only selects; m is a constant after unroll
                    f2 h_im1 = (m == 0) ? hA[k - 1][i] : (m == 1) ? hB[k - 1][i] : hn[m - 2][i];
                    f2 h_i   = (m == 0) ? hB[k - 1][i] : hn[m - 1][i];
                    f2 z = pkfma(W0, h_im1 + hn[m][i],
                           pkfma(W1, h_i, 10.f * orow[DEPTH - k + m][i]));
                    if (k < DEPTH) {
                        f2 t = tval(z);
                        tin[m][i] = rv ? t : f2{0.f, 0.f};
                    } else {
                        ufin[m][i] = uval(z);
                    }
                }
            }
            // carries for next step: hA <- h(yS-k+3), hB <- h(yS-k+4)
#pragma unroll
            for (int i = 0; i < 2; ++i) {
                hA[k - 1][i] = hn[2][i];
                hB[k - 1][i] = hn[3][i];
            }
        }

        // ---- store u rows r = yS-10+m inside this strip ----
#pragma unroll
        for (int m = 0; m < RB; ++m) {
            const int r = yS - DEPTH + m;
            if (r >= y0 && r < y0 + ROWS) {
                f4 v;
                v.x = ufin[m][0].x; v.y = ufin[m][0].y;
                v.z = ufin[m][1].x; v.w = ufin[m][1].y;
                *reinterpret_cast<f4*>(up_lane + r * Ww) = v;
            }
        }
    }
}

extern "C" void kernel_launch(void* const* d_in, const int* in_sizes, int n_in,
                              void* d_out, int out_size, void* d_ws, size_t ws_size,
                              hipStream_t stream) {
    (void)in_sizes; (void)n_in; (void)out_size; (void)d_ws; (void)ws_size;
    const float* o     = (const float*)d_in[0];
    const float* sigma = (const float*)d_in[1];
    const float* lam   = (const float*)d_in[2];
    float* out = (float*)d_out;

    k_fused<<<PLANES * STRIPS, 64, 0, stream>>>(o, sigma, lam, out);
}

// Round 5
// 242.566 us; speedup vs baseline: 3.3389x; 1.0523x over previous
//
#include <hip/hip_runtime.h>

typedef float f2 __attribute__((ext_vector_type(2)));
typedef float f4 __attribute__((ext_vector_type(4)));

static constexpr int Hh = 256, Ww = 256, HW = Hh * Ww;
static constexpr int PLANES = 512;            // N*C
static constexpr int STRIPS = 8;
static constexpr int ROWS   = Hh / STRIPS;    // 32
static constexpr int DEPTH  = 10;
static constexpr int RB     = 4;              // rows advanced per sweep step
static constexpr int NSTEP  = (ROWS + 2 * DEPTH) / RB;   // 13

#if __has_builtin(__builtin_amdgcn_exp2f)
#define EXP2F(x) __builtin_amdgcn_exp2f(x)
#else
#define EXP2F(x) __expf((x) * 0.6931471805599453f)
#endif
#if __has_builtin(__builtin_amdgcn_logf)
#define LOG2F(x) __builtin_amdgcn_logf(x)
#else
#define LOG2F(x) (__logf(x) * 1.4426950408889634f)
#endif

static constexpr float LN2 = 0.6931471805599453f;
static constexpr float L2E = 1.4426950408889634f;
static constexpr float AZS = 10.0f * L2E;     // BETA folded into exp2 arg

__device__ __forceinline__ f2 pkfma(f2 a, f2 b, f2 c) {
#if __has_builtin(__builtin_elementwise_fma)
    return __builtin_elementwise_fma(a, b, c);
#else
    return f2{fmaf(a.x, b.x, c.x), fmaf(a.y, b.y, c.y)};
#endif
}
__device__ __forceinline__ f2 pkmax(f2 a, f2 b) {
#if __has_builtin(__builtin_elementwise_max)
    return __builtin_elementwise_max(a, b);
#else
    return f2{fmaxf(a.x, b.x), fmaxf(a.y, b.y)};
#endif
}

// softplus(10z) pieces in base 2, z unscaled:
//   lg = log2(1 + 2^(-|z|*10*log2e)),  mz = max(z,0)
__device__ __forceinline__ void sp_parts(f2 z, f2& lg, f2& mz) {
    f2 az = pkmax(z, -z);
    f2 a  = az * AZS;
    f2 p;
    p.x = EXP2F(-a.x);
    p.y = EXP2F(-a.y);
    f2 op = p + 1.0f;
    lg.x = LOG2F(op.x);
    lg.y = LOG2F(op.y);
    mz = pkmax(z, f2{0.f, 0.f});
}
// t = 1 - 2*slrelu(z) = 1 - 0.4 z - 1.6 mz - 0.16*ln2 * lg
__device__ __forceinline__ f2 tval(f2 z) {
    f2 lg, mz;
    sp_parts(z, lg, mz);
    return pkfma(f2{-0.16f * LN2, -0.16f * LN2}, lg,
           pkfma(f2{-1.6f, -1.6f}, mz,
           pkfma(f2{-0.4f, -0.4f}, z, f2{1.f, 1.f})));
}
// u = slrelu(z) = 0.2 z + 0.8 mz + 0.08*ln2 * lg
__device__ __forceinline__ f2 uval(f2 z) {
    f2 lg, mz;
    sp_parts(z, lg, mz);
    return pkfma(f2{0.08f * LN2, 0.08f * LN2}, lg,
           pkfma(f2{0.8f, 0.8f}, mz, f2{0.2f, 0.2f} * z));
}

__global__ __launch_bounds__(64, 3)
void k_fused(const float* __restrict__ o, const float* __restrict__ sigma,
             const float* __restrict__ lam, float* __restrict__ out) {
    const int lane  = threadIdx.x;
    const int bid   = blockIdx.x;
    const int plane = bid >> 3;               // 512 planes
    const int strip = bid & 7;
    const int y0    = strip * ROWS;
    const int x0    = lane * 4;
    const int ch    = plane & 63;

    float s   = fmaxf(sigma[ch], 1e-6f);
    float eg  = __expf(-1.0f / (2.0f * s * s));
    float inv = 1.0f / (1.0f + 2.0f * eg);
    const float w0s = eg * inv, w1s = inv, l = lam[0];
    const f2 w0 = f2{w0s, w0s}, w1 = f2{w1s, w1s};
    const f2 W0 = f2{-l * w0s, -l * w0s};     // vertical taps, -lam folded
    const f2 W1 = f2{-l * w1s, -l * w1s};

    const float* op_lane = o   + plane * HW + x0;
    float*       up_lane = out + plane * HW + x0;
    const int a_up = ((lane + 63) & 63) << 2;
    const int a_dn = ((lane + 1)  & 63) << 2;

    // per-stage h carries in LDS: [stage][rowA/rowB][lane] -> 4 px as f4
    __shared__ f4 hc[DEPTH][2][64];
#pragma unroll
    for (int k = 0; k < DEPTH; ++k) {
        hc[k][0][lane] = f4{0.f, 0.f, 0.f, 0.f};
        hc[k][1][lane] = f4{0.f, 0.f, 0.f, 0.f};
    }

#pragma unroll 1
    for (int j = 0; j < NSTEP; ++j) {
        const int yS = y0 - DEPTH + RB * j;   // fresh stage-0 rows yS..yS+3

        // ---- load o rows yS-10 .. yS+3 (14 rows), row index clamped;
        //      OOB rows yield garbage that is masked before any valid use ----
        f2 orow[DEPTH + RB][2];
#pragma unroll
        for (int t = 0; t < DEPTH + RB; ++t) {
            int r = yS - DEPTH + t;
            r = r < 0 ? 0 : (r > 255 ? 255 : r);      // wave-uniform clamp
            f4 v = *reinterpret_cast<const f4*>(op_lane + r * Ww);
            orow[t][0] = f2{v.x, v.y};
            orow[t][1] = f2{v.z, v.w};
        }
        asm volatile("" ::: "memory");   // keep the load batch up top

        // ---- stage 0: t0 rows yS..yS+3 (orow slots 10..13) ----
        f2 tin[RB][2];
#pragma unroll
        for (int m = 0; m < RB; ++m) {
            const bool rv = (unsigned)(yS + m) < 256u;
#pragma unroll
            for (int i = 0; i < 2; ++i) {
                f2 t = tval(orow[DEPTH + m][i]);
                tin[m][i] = rv ? t : f2{0.f, 0.f};
            }
        }

        f2 ufin[RB][2];
        // ---- stages 1..10 ----
#pragma unroll
        for (int k = 1; k <= DEPTH; ++k) {
            // horizontal conv of the 4 incoming t rows -> hn[m] = h(yS-k+1+m)
            f2 hn[RB][2];
#pragma unroll
            for (int m = 0; m < RB; ++m) {
                const f2 t0 = tin[m][0], t1 = tin[m][1];
                float lft = __int_as_float(__builtin_amdgcn_ds_bpermute(a_up, __float_as_int(t1.y)));
                float rgt = __int_as_float(__builtin_amdgcn_ds_bpermute(a_dn, __float_as_int(t0.x)));
                lft = (lane == 0)  ? 0.f : lft;
                rgt = (lane == 63) ? 0.f : rgt;
                f2 tl0 = {lft,  t0.x};
                f2 mid = {t0.y, t1.x};
                f2 tr1 = {t1.y, rgt};
                hn[m][0] = pkfma(w1, t0, w0 * (tl0 + mid));
                hn[m][1] = pkfma(w1, t1, w0 * (mid + tr1));
            }

            // carries: hA = h(yS-k-1), hB = h(yS-k) from LDS
            const f4 cA = hc[k - 1][0][lane];
            const f4 cB = hc[k - 1][1][lane];
            const f2 hA[2] = {f2{cA.x, cA.y}, f2{cA.z, cA.w}};
            const f2 hB[2] = {f2{cB.x, cB.y}, f2{cB.z, cB.w}};

#pragma unroll
            for (int m = 0; m < RB; ++m) {
                const int r = yS - k + m;
                const bool rv = (unsigned)r < 256u;
#pragma unroll
                for (int i = 0; i < 2; ++i) {
                    f2 h_im1 = (m == 0) ? hA[i] : (m == 1) ? hB[i] : hn[m - 2][i];
                    f2 h_i   = (m == 0) ? hB[i] : hn[m - 1][i];
                    // z = o[r] - lam*q  (BETA folded into tval/uval)
                    f2 z = pkfma(W0, h_im1 + hn[m][i],
                           pkfma(W1, h_i, orow[DEPTH - k + m][i]));
                    if (k < DEPTH) {
                        f2 t = tval(z);
                        tin[m][i] = rv ? t : f2{0.f, 0.f};
                    } else {
                        ufin[m][i] = uval(z);
                    }
                }
            }

            // write next step's carries: hA <- h(yS-k+3)=hn[2], hB <- hn[3]
            hc[k - 1][0][lane] = f4{hn[2][0].x, hn[2][0].y, hn[2][1].x, hn[2][1].y};
            hc[k - 1][1][lane] = f4{hn[3][0].x, hn[3][0].y, hn[3][1].x, hn[3][1].y};
        }

        // ---- store u rows r = yS-10+m inside this strip ----
#pragma unroll
        for (int m = 0; m < RB; ++m) {
            const int r = yS - DEPTH + m;
            if (r >= y0 && r < y0 + ROWS) {
                f4 v;
                v.x = ufin[m][0].x; v.y = ufin[m][0].y;
                v.z = ufin[m][1].x; v.w = ufin[m][1].y;
                *reinterpret_cast<f4*>(up_lane + r * Ww) = v;
            }
        }
    }
}

extern "C" void kernel_launch(void* const* d_in, const int* in_sizes, int n_in,
                              void* d_out, int out_size, void* d_ws, size_t ws_size,
                              hipStream_t stream) {
    (void)in_sizes; (void)n_in; (void)out_size; (void)d_ws; (void)ws_size;
    const float* o     = (const float*)d_in[0];
    const float* sigma = (const float*)d_in[1];
    const float* lam   = (const float*)d_in[2];
    float* out = (float*)d_out;

    k_fused<<<PLANES * STRIPS, 64, 0, stream>>>(o, sigma, lam, out);
}